// Round 8
// baseline (175.231 us; speedup 1.0000x reference)
//
#include <hip/hip_runtime.h>
#include <stdint.h>

#define B_  64
#define T_  256
#define C_  384
#define H_  6
#define D_  64
#define NTOK (B_*T_)   // 16384

typedef float f32x4  __attribute__((ext_vector_type(4)));
typedef short s16x8  __attribute__((ext_vector_type(8)));

__device__ __forceinline__ unsigned short f2bf(float f) {
    unsigned int u;
    __builtin_memcpy(&u, &f, 4);
    u = u + 0x7FFFu + ((u >> 16) & 1u);   // RNE
    return (unsigned short)(u >> 16);
}

// async 16B global -> LDS (lane i lands at ldsbase + i*16)
__device__ __forceinline__ void async_copy16(const unsigned short* g, unsigned short* l) {
    __builtin_amdgcn_global_load_lds(
        (const __attribute__((address_space(1))) unsigned int*)g,
        (__attribute__((address_space(3))) unsigned int*)l, 16, 0, 0);
}

// ---------------------------------------------------------------------------
// Kernel 0: convert + transpose weights f32 [R][Cc] -> bf16 [Cc][R].
// (verbatim R5)
// ---------------------------------------------------------------------------
__global__ __launch_bounds__(256) void transpose_weights(
    const float* __restrict__ Wq, const float* __restrict__ Wk,
    const float* __restrict__ Wv, const float* __restrict__ Wp,
    unsigned short* __restrict__ W3, unsigned short* __restrict__ WTp) {
    __shared__ float tile[32][33];
    int z = blockIdx.y;
    const float* in;
    unsigned short* out;
    int R, Cc;
    if (z < 18) {
        int proj = z / 6, h = z % 6;
        const float* Wsrc = proj == 0 ? Wq : (proj == 1 ? Wk : Wv);
        in = Wsrc + h * C_ * D_;
        out = W3 + (size_t)(h * 192 + proj * 64) * C_;
        R = C_; Cc = D_;
    } else {
        in = Wp; out = WTp; R = C_; Cc = C_;
    }
    int tilesC = Cc / 32;
    int tilesR = R / 32;
    int bx = blockIdx.x;
    if (bx >= tilesC * tilesR) return;
    int tr = bx / tilesC, tc = bx % tilesC;
    int tx = threadIdx.x & 31;
    int ty8 = threadIdx.x >> 5;
    int gx = tc * 32 + tx;
#pragma unroll
    for (int i = 0; i < 4; i++) {
        int gy = tr * 32 + ty8 + i * 8;
        tile[ty8 + i * 8][tx] = in[gy * Cc + gx];
    }
    __syncthreads();
#pragma unroll
    for (int i = 0; i < 4; i++) {
        int oy = tc * 32 + ty8 + i * 8;
        int ox = tr * 32 + tx;
        out[oy * R + ox] = f2bf(tile[tx][ty8 + i * 8]);
    }
}

// ---------------------------------------------------------------------------
// Kernel 1: FUSED per-(b,h) QKV projection + causal attention.
// R5 base (proven 54us): 76KB LDS -> 2 independent blocks/CU; 8-wave
// dual-tile; Wc [192][32] DMA staging; q in-register via ds_bpermute.
// R8 = R7's counted-vmcnt scheme with the two correctness holes closed:
//  (1) kc=11 PEELED: the loop (kc=0..10) always prefetches real kc+1 data
//      (no dead loads for DCE to delete -- R7's dummy-prefetch was DCE'd,
//      making vmcnt(4) a no-op on the last chunk -> race, absmax 0.12);
//  (2) sched_barrier(0) fences after entry-barrier / DMA issue / prefetch
//      issue pin region order, so "DMAs are older than the 4 newest A-loads"
//      holds and vmcnt(4) provably drains all DMAs (w<4: 2+4=6->4; w>=4:
//      1+4=5->4).  Peeled chunk: convert (drains prev-A) -> vmcnt(0) (only
//      DMAs outstanding) -> barrier -> MFMA.
// No arithmetic change -> bit-identical output vs R5.
// ---------------------------------------------------------------------------
__global__ __launch_bounds__(512, 4) void fused_attn(
    const float* __restrict__ X, const unsigned short* __restrict__ W3,
    unsigned short* __restrict__ Ows) {
    __shared__ alignas(16) unsigned short smem[38912];   // 76 KB -> 2 blocks/CU
    unsigned short* Wc     = smem;            // [192][32] staging; pw aliases post-barrier
    unsigned short* k_lds  = smem + 6144;     // [256][64]
    unsigned short* vT_lds = k_lds + 16384;   // [64][256]

    int bh = blockIdx.x;
    int h = bh >> 6, b = bh & 63;
    int tid = threadIdx.x;
    int w = tid >> 6, lane = tid & 63;
    int n16 = lane & 15, q4 = lane >> 4;
    const int jt[2] = {w, 15 - w};            // this wave's token-tiles (both phases)

    const unsigned short* W3h = W3 + (size_t)h * 192 * C_;
    const float* xb = X + (size_t)b * T_ * C_;

    f32x4 acc[2][12];
#pragma unroll
    for (int i = 0; i < 2; i++)
#pragma unroll
        for (int jj = 0; jj < 12; jj++) acc[i][jj] = (f32x4){0.f, 0.f, 0.f, 0.f};

    // ---------------- Phase A: q/k/v projection, 12 chunks of K=32 --------
    float4 a0[2], a1[2];
#pragma unroll
    for (int mi = 0; mi < 2; mi++) {          // preload chunk 0 A-frags
        const float* ap = xb + (size_t)(jt[mi] * 16 + n16) * C_ + q4 * 8;
        a0[mi] = *reinterpret_cast<const float4*>(ap);
        a1[mi] = *reinterpret_cast<const float4*>(ap + 4);
    }

    for (int kc = 0; kc < 11; kc++) {
        int ko = kc * 32;
        if (kc) {
            // prev chunk's Wc ds_reads complete (consumed by MFMA operand
            // waits); raw barrier keeps vmem (A-prefetch) in flight
            asm volatile("s_waitcnt lgkmcnt(0)" ::: "memory");
            __builtin_amdgcn_s_barrier();
            __builtin_amdgcn_sched_barrier(0);
        }
        // ---- region 1: DMA issue (oldest vmem ops of this iteration) ----
        {
            int L = w * 64 + lane;
            int row = L >> 2, c = L & 3;
            async_copy16(W3h + (size_t)row * C_ + ko + ((c ^ (row & 3)) * 8),
                         Wc + (size_t)L * 8);
            if (w < 4) {
                int L2 = 512 + w * 64 + lane;
                int row2 = L2 >> 2, c2 = L2 & 3;
                async_copy16(W3h + (size_t)row2 * C_ + ko + ((c2 ^ (row2 & 3)) * 8),
                             Wc + (size_t)L2 * 8);
            }
        }
        __builtin_amdgcn_sched_barrier(0);   // pin: nothing hoists above DMAs
        // ---- region 2: convert this chunk's A (waits only prev-A, older
        // than the DMAs) + issue next chunk's 4 A-loads (newest) ----------
        s16x8 af[2];
#pragma unroll
        for (int mi = 0; mi < 2; mi++) {
            float4 lo = a0[mi], hi = a1[mi];
            s16x8 a;
            a[0] = (short)f2bf(lo.x); a[1] = (short)f2bf(lo.y);
            a[2] = (short)f2bf(lo.z); a[3] = (short)f2bf(lo.w);
            a[4] = (short)f2bf(hi.x); a[5] = (short)f2bf(hi.y);
            a[6] = (short)f2bf(hi.z); a[7] = (short)f2bf(hi.w);
            af[mi] = a;
        }
#pragma unroll
        for (int mi = 0; mi < 2; mi++) {
            const float* ap = xb + (size_t)(jt[mi] * 16 + n16) * C_ + (ko + 32) + q4 * 8;
            a0[mi] = *reinterpret_cast<const float4*>(ap);
            a1[mi] = *reinterpret_cast<const float4*>(ap + 4);
        }
        __builtin_amdgcn_sched_barrier(0);   // pin: prefetch issued before wait
        // counted drain: outstanding = [DMA x1-2, A x4]; vmcnt(4) completes
        // all DMAs for every wave, A-prefetch keeps flying across the barrier
        asm volatile("s_waitcnt vmcnt(4)" ::: "memory");
        __builtin_amdgcn_s_barrier();
        __builtin_amdgcn_sched_barrier(0);
        __builtin_amdgcn_s_setprio(1);
#pragma unroll
        for (int ni = 0; ni < 12; ni++) {
            int row = ni * 16 + n16;
            s16x8 bf = *reinterpret_cast<const s16x8*>(&Wc[row * 32 + ((q4 ^ (row & 3)) * 8)]);
            if (ni < 8) {   // q,k: swapped -> lane = token
                acc[0][ni] = __builtin_amdgcn_mfma_f32_16x16x32_bf16(bf, af[0], acc[0][ni], 0, 0, 0);
                acc[1][ni] = __builtin_amdgcn_mfma_f32_16x16x32_bf16(bf, af[1], acc[1][ni], 0, 0, 0);
            } else {        // v: normal -> lane = d-col
                acc[0][ni] = __builtin_amdgcn_mfma_f32_16x16x32_bf16(af[0], bf, acc[0][ni], 0, 0, 0);
                acc[1][ni] = __builtin_amdgcn_mfma_f32_16x16x32_bf16(af[1], bf, acc[1][ni], 0, 0, 0);
            }
        }
        __builtin_amdgcn_s_setprio(0);
    }
    // ---- peeled kc=11: no prefetch, full vmem drain (only DMAs in flight) -
    {
        int ko = 11 * 32;
        asm volatile("s_waitcnt lgkmcnt(0)" ::: "memory");
        __builtin_amdgcn_s_barrier();
        __builtin_amdgcn_sched_barrier(0);
        {
            int L = w * 64 + lane;
            int row = L >> 2, c = L & 3;
            async_copy16(W3h + (size_t)row * C_ + ko + ((c ^ (row & 3)) * 8),
                         Wc + (size_t)L * 8);
            if (w < 4) {
                int L2 = 512 + w * 64 + lane;
                int row2 = L2 >> 2, c2 = L2 & 3;
                async_copy16(W3h + (size_t)row2 * C_ + ko + ((c2 ^ (row2 & 3)) * 8),
                             Wc + (size_t)L2 * 8);
            }
        }
        __builtin_amdgcn_sched_barrier(0);
        s16x8 af[2];
#pragma unroll
        for (int mi = 0; mi < 2; mi++) {
            float4 lo = a0[mi], hi = a1[mi];
            s16x8 a;
            a[0] = (short)f2bf(lo.x); a[1] = (short)f2bf(lo.y);
            a[2] = (short)f2bf(lo.z); a[3] = (short)f2bf(lo.w);
            a[4] = (short)f2bf(hi.x); a[5] = (short)f2bf(hi.y);
            a[6] = (short)f2bf(hi.z); a[7] = (short)f2bf(hi.w);
            af[mi] = a;
        }
        __builtin_amdgcn_sched_barrier(0);
        asm volatile("s_waitcnt vmcnt(0)" ::: "memory");
        __builtin_amdgcn_s_barrier();
        __builtin_amdgcn_sched_barrier(0);
        __builtin_amdgcn_s_setprio(1);
#pragma unroll
        for (int ni = 0; ni < 12; ni++) {
            int row = ni * 16 + n16;
            s16x8 bf = *reinterpret_cast<const s16x8*>(&Wc[row * 32 + ((q4 ^ (row & 3)) * 8)]);
            if (ni < 8) {
                acc[0][ni] = __builtin_amdgcn_mfma_f32_16x16x32_bf16(bf, af[0], acc[0][ni], 0, 0, 0);
                acc[1][ni] = __builtin_amdgcn_mfma_f32_16x16x32_bf16(bf, af[1], acc[1][ni], 0, 0, 0);
            } else {
                acc[0][ni] = __builtin_amdgcn_mfma_f32_16x16x32_bf16(af[0], bf, acc[0][ni], 0, 0, 0);
                acc[1][ni] = __builtin_amdgcn_mfma_f32_16x16x32_bf16(af[1], bf, acc[1][ni], 0, 0, 0);
            }
        }
        __builtin_amdgcn_s_setprio(0);
    }

    // epilogue: k/vT scatter (verbatim proven), q kept in registers
    unsigned int qd[2][4][2];   // [tile][ni][dword]; all indices unroll-const
#pragma unroll
    for (int mi = 0; mi < 2; mi++) {
        int tile = jt[mi];
#pragma unroll
        for (int ni = 0; ni < 12; ni++) {
            ushort4 pk;
            pk.x = f2bf(acc[mi][ni][0]); pk.y = f2bf(acc[mi][ni][1]);
            pk.z = f2bf(acc[mi][ni][2]); pk.w = f2bf(acc[mi][ni][3]);
            if (ni < 4) {
                qd[mi][ni][0] = (unsigned int)pk.x | ((unsigned int)pk.y << 16);
                qd[mi][ni][1] = (unsigned int)pk.z | ((unsigned int)pk.w << 16);
            } else if (ni < 8) {
                int t = tile * 16 + n16;                       // lane = token
                int cp = (2 * (ni & 3) + (q4 >> 1)) ^ (n16 & 7);
                *reinterpret_cast<ushort4*>(&k_lds[t * 64 + cp * 8 + (q4 & 1) * 4]) = pk;
            } else {
                int d = (ni - 8) * 16 + n16;                   // lane = d
                int cp = (tile * 2 + (q4 >> 1)) ^ (d & 7);
                *reinterpret_cast<ushort4*>(&vT_lds[d * 256 + cp * 8 + (q4 & 1) * 4]) = pk;
            }
        }
    }

    // in-register q relayout: C/D frag (d = ni*16+q4*4+r) -> A-frag
    // (qa0: d = q4*8..+7, qa1: d = 32+q4*8..+7), same token row n16.
    s16x8 qa[2][2];
    {
        int addrA = (n16 + 32 * (q4 & 1)) * 4;
        int addrB = addrA + 64;
        bool hi = (q4 & 2) != 0;
#pragma unroll
        for (int mi = 0; mi < 2; mi++) {
#pragma unroll
            for (int half = 0; half < 2; half++) {
                unsigned int s0x = qd[mi][half * 2][0],     s0y = qd[mi][half * 2][1];
                unsigned int s1x = qd[mi][half * 2 + 1][0], s1y = qd[mi][half * 2 + 1][1];
                unsigned int A0x = (unsigned int)__builtin_amdgcn_ds_bpermute(addrA, (int)s0x);
                unsigned int A1x = (unsigned int)__builtin_amdgcn_ds_bpermute(addrA, (int)s1x);
                unsigned int A0y = (unsigned int)__builtin_amdgcn_ds_bpermute(addrA, (int)s0y);
                unsigned int A1y = (unsigned int)__builtin_amdgcn_ds_bpermute(addrA, (int)s1y);
                unsigned int B0x = (unsigned int)__builtin_amdgcn_ds_bpermute(addrB, (int)s0x);
                unsigned int B1x = (unsigned int)__builtin_amdgcn_ds_bpermute(addrB, (int)s1x);
                unsigned int B0y = (unsigned int)__builtin_amdgcn_ds_bpermute(addrB, (int)s0y);
                unsigned int B1y = (unsigned int)__builtin_amdgcn_ds_bpermute(addrB, (int)s1y);
                unsigned int t[4];
                t[0] = hi ? A1x : A0x;
                t[1] = hi ? A1y : A0y;
                t[2] = hi ? B1x : B0x;
                t[3] = hi ? B1y : B0y;
                s16x8 q;
                __builtin_memcpy(&q, t, 16);
                qa[mi][half] = q;
            }
        }
    }
    __syncthreads();   // full drain; k/vT/pw region visible to all waves

    // ---------------- Phase B: causal attention from LDS ----------------
    unsigned short* pw = smem + w * 640;   // aliases Wc region; safe post-barrier
    const f32x4 zero4 = (f32x4){0.f, 0.f, 0.f, 0.f};

#pragma unroll
    for (int tt = 0; tt < 2; tt++) {
        int j = jt[tt];
        int t0 = j * 16;
        s16x8 qa0 = qa[tt][0];
        s16x8 qa1 = qa[tt][1];

        f32x4 o[4];
        float l_lane[4];
#pragma unroll
        for (int i = 0; i < 4; i++) o[i] = zero4;
#pragma unroll
        for (int r = 0; r < 4; r++) l_lane[r] = 0.f;

        int nch = j / 2 + 1;
        for (int c = 0; c < nch; c++) {
            int s0 = c * 32;
            bool bAct = (s0 + 16) < (t0 + 16);
            int r0 = s0 + n16, r1 = s0 + 16 + n16;
            s16x8 k00 = *reinterpret_cast<const s16x8*>(&k_lds[r0 * 64 + ((q4 ^ (r0 & 7)) * 8)]);
            s16x8 k01 = *reinterpret_cast<const s16x8*>(&k_lds[r0 * 64 + (((q4 + 4) ^ (r0 & 7)) * 8)]);
            __builtin_amdgcn_s_setprio(1);
            f32x4 sv0 = __builtin_amdgcn_mfma_f32_16x16x32_bf16(qa0, k00, zero4, 0, 0, 0);
            sv0 = __builtin_amdgcn_mfma_f32_16x16x32_bf16(qa1, k01, sv0, 0, 0, 0);
            __builtin_amdgcn_s_setprio(0);
            f32x4 sv1 = zero4;
            if (bAct) {
                s16x8 k10 = *reinterpret_cast<const s16x8*>(&k_lds[r1 * 64 + ((q4 ^ (r1 & 7)) * 8)]);
                s16x8 k11 = *reinterpret_cast<const s16x8*>(&k_lds[r1 * 64 + (((q4 + 4) ^ (r1 & 7)) * 8)]);
                __builtin_amdgcn_s_setprio(1);
                sv1 = __builtin_amdgcn_mfma_f32_16x16x32_bf16(qa0, k10, zero4, 0, 0, 0);
                sv1 = __builtin_amdgcn_mfma_f32_16x16x32_bf16(qa1, k11, sv1, 0, 0, 0);
                __builtin_amdgcn_s_setprio(0);
            }
#pragma unroll
            for (int r = 0; r < 4; r++) {
                int t = t0 + q4 * 4 + r;
                float pA = (s0 + n16 <= t) ? __expf(sv0[r] * 0.125f) : 0.f;
                float pB = (bAct && (s0 + 16 + n16 <= t)) ? __expf(sv1[r] * 0.125f) : 0.f;
                l_lane[r] += pA + pB;
                pw[(q4 * 4 + r) * 40 + n16] = f2bf(pA);
                pw[(q4 * 4 + r) * 40 + 16 + n16] = f2bf(pB);
            }
            s16x8 pa = *reinterpret_cast<const s16x8*>(&pw[n16 * 40 + q4 * 8]);
            __builtin_amdgcn_s_setprio(1);
#pragma unroll
            for (int dt = 0; dt < 4; dt++) {
                int d = dt * 16 + n16;
                int jp = (c * 4 + q4) ^ (d & 7);
                s16x8 vf = *reinterpret_cast<const s16x8*>(&vT_lds[d * 256 + jp * 8]);
                o[dt] = __builtin_amdgcn_mfma_f32_16x16x32_bf16(pa, vf, o[dt], 0, 0, 0);
            }
            __builtin_amdgcn_s_setprio(0);
        }

        float linv[4];
#pragma unroll
        for (int r = 0; r < 4; r++) {
            float l = l_lane[r];
            l += __shfl_xor(l, 1);
            l += __shfl_xor(l, 2);
            l += __shfl_xor(l, 4);
            l += __shfl_xor(l, 8);
            linv[r] = 1.0f / l;
        }
#pragma unroll
        for (int dt = 0; dt < 4; dt++) {
            int col = h * 64 + dt * 16 + n16;
#pragma unroll
            for (int r = 0; r < 4; r++)
                Ows[(size_t)(b * T_ + t0 + q4 * 4 + r) * C_ + col] = f2bf(o[dt][r] * linv[r]);
        }
    }
}

// ---------------------------------------------------------------------------
// Kernel 2: output projection + bias -> f32.  (verbatim R5)
// ---------------------------------------------------------------------------
__global__ __launch_bounds__(256) void gemm_out(
    const unsigned short* __restrict__ A, const unsigned short* __restrict__ WTp,
    const float* __restrict__ bp, float* __restrict__ out) {
    __shared__ alignas(16) unsigned short Bt[6 * 128 * 32];   // 48 KB
    int m0 = blockIdx.x * 128;
    int n0 = blockIdx.y * 128;
    int tid = threadIdx.x;
    int w = tid >> 6, lane = tid & 63;
    int n16 = lane & 15, q4 = lane >> 4;

    f32x4 acc[2][8];
#pragma unroll
    for (int i = 0; i < 2; i++)
#pragma unroll
        for (int j = 0; j < 8; j++) acc[i][j] = (f32x4){0.f, 0.f, 0.f, 0.f};

    const unsigned short* a_base[2];
#pragma unroll
    for (int mi = 0; mi < 2; mi++)
        a_base[mi] = A + (size_t)(m0 + w * 32 + mi * 16 + n16) * C_ + q4 * 8;

    for (int half = 0; half < 2; half++) {
        int ko = half * 192;
        s16x8 af[2][6];
#pragma unroll
        for (int mi = 0; mi < 2; mi++)
#pragma unroll
            for (int ks = 0; ks < 6; ks++)
                af[mi][ks] = *reinterpret_cast<const s16x8*>(a_base[mi] + ko + ks * 32);
        if (half) __syncthreads();
#pragma unroll
        for (int i = 0; i < 12; i++) {
            int L = w * 768 + i * 64 + lane;
            int kstep = L >> 9;
            int rem = L & 511;
            int row = rem >> 2;
            int j = (rem & 3) ^ (row & 3);
            async_copy16(WTp + (size_t)(n0 + row) * C_ + ko + kstep * 32 + j * 8,
                         Bt + (size_t)(w * 768 + i * 64) * 8);
        }
        __syncthreads();
#pragma unroll
        for (int ks = 0; ks < 6; ks++) {
            s16x8 bf[8];
#pragma unroll
            for (int ni = 0; ni < 8; ni++) {
                int row = ni * 16 + n16;
                int jp = q4 ^ (row & 3);
                bf[ni] = *reinterpret_cast<const s16x8*>(&Bt[ks * 4096 + row * 32 + jp * 8]);
            }
#pragma unroll
            for (int mi = 0; mi < 2; mi++)
#pragma unroll
                for (int ni = 0; ni < 8; ni++)
                    acc[mi][ni] = __builtin_amdgcn_mfma_f32_16x16x32_bf16(
                        bf[ni], af[mi][ks], acc[mi][ni], 0, 0, 0);
        }
    }

#pragma unroll
    for (int mi = 0; mi < 2; mi++) {
        int tr = m0 + w * 32 + mi * 16 + n16;
#pragma unroll
        for (int ni = 0; ni < 8; ni++) {
            int c0 = n0 + ni * 16 + q4 * 4;
            float4 bias = *reinterpret_cast<const float4*>(&bp[c0]);
            float4 res;
            res.x = acc[mi][ni][0] + bias.x;
            res.y = acc[mi][ni][1] + bias.y;
            res.z = acc[mi][ni][2] + bias.z;
            res.w = acc[mi][ni][3] + bias.w;
            *reinterpret_cast<float4*>(&out[(size_t)tr * C_ + c0]) = res;
        }
    }
}

// ---------------------------------------------------------------------------
extern "C" void kernel_launch(void* const* d_in, const int* in_sizes, int n_in,
                              void* d_out, int out_size, void* d_ws, size_t ws_size,
                              hipStream_t stream) {
    const float* x  = (const float*)d_in[0];
    const float* Wq = (const float*)d_in[1];
    const float* Wk = (const float*)d_in[2];
    const float* Wv = (const float*)d_in[3];
    const float* Wp = (const float*)d_in[4];
    const float* bp = (const float*)d_in[5];
    float* out = (float*)d_out;

    char* ws = (char*)d_ws;
    size_t off = 0;
    auto alloc = [&](size_t bytes) -> unsigned short* {
        unsigned short* p = (unsigned short*)(ws + off);
        off += (bytes + 255) & ~(size_t)255;
        return p;
    };
    unsigned short* W3  = alloc((size_t)H_ * 192 * C_ * 2);  // 884 KB
    unsigned short* WTp = alloc((size_t)C_ * C_ * 2);        // 295 KB
    unsigned short* Ows = alloc((size_t)NTOK * C_ * 2);      // 12.6 MB

    transpose_weights<<<dim3(144, 19), dim3(256), 0, stream>>>(
        Wq, Wk, Wv, Wp, W3, WTp);
    fused_attn<<<dim3(B_ * H_), dim3(512), 0, stream>>>(x, W3, Ows);
    gemm_out<<<dim3(128, 3), dim3(256), 0, stream>>>(Ows, WTp, bp, out);
}

// Round 10
// 145.790 us; speedup vs baseline: 1.2019x; 1.2019x over previous
//
#include <hip/hip_runtime.h>
#include <stdint.h>

#define B_  64
#define T_  256
#define C_  384
#define H_  6
#define D_  64
#define NTOK (B_*T_)   // 16384

typedef float f32x4  __attribute__((ext_vector_type(4)));
typedef short s16x8  __attribute__((ext_vector_type(8)));

__device__ __forceinline__ unsigned short f2bf(float f) {
    unsigned int u;
    __builtin_memcpy(&u, &f, 4);
    u = u + 0x7FFFu + ((u >> 16) & 1u);   // RNE
    return (unsigned short)(u >> 16);
}

// async 16B global -> LDS (lane i lands at ldsbase + i*16)
__device__ __forceinline__ void async_copy16(const unsigned short* g, unsigned short* l) {
    __builtin_amdgcn_global_load_lds(
        (const __attribute__((address_space(1))) unsigned int*)g,
        (__attribute__((address_space(3))) unsigned int*)l, 16, 0, 0);
}

// ---------------------------------------------------------------------------
// Kernel 0: convert + transpose weights f32 [R][Cc] -> bf16 [Cc][R].
// z<18: per-(proj,head) 384x64 -> W3 [h][proj*64+d][k]; z==18: Wp -> WTp.
// (R5-exact)
// ---------------------------------------------------------------------------
__global__ __launch_bounds__(256) void transpose_weights(
    const float* __restrict__ Wq, const float* __restrict__ Wk,
    const float* __restrict__ Wv, const float* __restrict__ Wp,
    unsigned short* __restrict__ W3, unsigned short* __restrict__ WTp) {
    __shared__ float tile[32][33];
    int z = blockIdx.y;
    const float* in;
    unsigned short* out;
    int R, Cc;
    if (z < 18) {
        int proj = z / 6, h = z % 6;
        const float* Wsrc = proj == 0 ? Wq : (proj == 1 ? Wk : Wv);
        in = Wsrc + h * C_ * D_;
        out = W3 + (size_t)(h * 192 + proj * 64) * C_;
        R = C_; Cc = D_;
    } else {
        in = Wp; out = WTp; R = C_; Cc = C_;
    }
    int tilesC = Cc / 32;
    int tilesR = R / 32;
    int bx = blockIdx.x;
    if (bx >= tilesC * tilesR) return;
    int tr = bx / tilesC, tc = bx % tilesC;
    int tx = threadIdx.x & 31;
    int ty8 = threadIdx.x >> 5;
    int gx = tc * 32 + tx;
#pragma unroll
    for (int i = 0; i < 4; i++) {
        int gy = tr * 32 + ty8 + i * 8;
        tile[ty8 + i * 8][tx] = in[gy * Cc + gx];
    }
    __syncthreads();
#pragma unroll
    for (int i = 0; i < 4; i++) {
        int oy = tc * 32 + ty8 + i * 8;
        int ox = tr * 32 + tx;
        out[oy * R + ox] = f2bf(tile[tx][ty8 + i * 8]);
    }
}

// ---------------------------------------------------------------------------
// Kernel 1: FUSED per-(b,h) QKV projection + causal attention.  (R5-exact,
// the session's best verified state: fused 54us / total 145us.)
// 76KB LDS -> 2 independent blocks/CU (separate barrier domains overlap
// each other's stalls; single dispatch round).  8-wave dual-tile (wave w
// owns tiles {w,15-w} in both phases).  Wc chunk [192][32]=12KB, 12 kc,
// DMA/XOR staging; A-loads pipelined one chunk ahead.  q never touches LDS
// (in-register C/D->A-frag relayout via ds_bpermute).  pw single-buffer
// 8x1280B aliases the Wc region post-barrier.
// Lever ledger (counters, R0-R9): occupancy x2 null (R1); DS-halving
// negative (R2); global-direct B negative (R3); counted-vmcnt raced (R7) /
// spilled 75MB scratch (R8) -- abandoned; Ows write-vectorization
// mis-ordered (R9) -- abandoned; gemm/transpose restructure null (R6).
// ---------------------------------------------------------------------------
__global__ __launch_bounds__(512, 4) void fused_attn(
    const float* __restrict__ X, const unsigned short* __restrict__ W3,
    unsigned short* __restrict__ Ows) {
    __shared__ alignas(16) unsigned short smem[38912];   // 76 KB -> 2 blocks/CU
    unsigned short* Wc     = smem;            // [192][32] staging; pw aliases post-barrier
    unsigned short* k_lds  = smem + 6144;     // [256][64]
    unsigned short* vT_lds = k_lds + 16384;   // [64][256]

    int bh = blockIdx.x;
    int h = bh >> 6, b = bh & 63;
    int tid = threadIdx.x;
    int w = tid >> 6, lane = tid & 63;
    int n16 = lane & 15, q4 = lane >> 4;
    const int jt[2] = {w, 15 - w};            // this wave's token-tiles (both phases)

    const unsigned short* W3h = W3 + (size_t)h * 192 * C_;
    const float* xb = X + (size_t)b * T_ * C_;

    f32x4 acc[2][12];
#pragma unroll
    for (int i = 0; i < 2; i++)
#pragma unroll
        for (int jj = 0; jj < 12; jj++) acc[i][jj] = (f32x4){0.f, 0.f, 0.f, 0.f};

    // ---------------- Phase A: q/k/v projection, 12 chunks of K=32 --------
    float4 a0[2], a1[2];
#pragma unroll
    for (int mi = 0; mi < 2; mi++) {          // preload chunk 0 A-frags
        const float* ap = xb + (size_t)(jt[mi] * 16 + n16) * C_ + q4 * 8;
        a0[mi] = *reinterpret_cast<const float4*>(ap);
        a1[mi] = *reinterpret_cast<const float4*>(ap + 4);
    }

    for (int kc = 0; kc < 12; kc++) {
        int ko = kc * 32;
        if (kc) __syncthreads();   // prev chunk's readers done
        // stage W chunk [192 rows][4 units of 16B]; slot L: row=L>>2, phys
        // unit c=L&3 holds logical unit c^(row&3)
        {
            int L = w * 64 + lane;
            int row = L >> 2, c = L & 3;
            async_copy16(W3h + (size_t)row * C_ + ko + ((c ^ (row & 3)) * 8),
                         Wc + (size_t)L * 8);
            if (w < 4) {
                int L2 = 512 + w * 64 + lane;
                int row2 = L2 >> 2, c2 = L2 & 3;
                async_copy16(W3h + (size_t)row2 * C_ + ko + ((c2 ^ (row2 & 3)) * 8),
                             Wc + (size_t)L2 * 8);
            }
        }
        __syncthreads();   // drains DMA (+ A-loads issued one chunk ago)
        s16x8 af[2];
#pragma unroll
        for (int mi = 0; mi < 2; mi++) {
            float4 lo = a0[mi], hi = a1[mi];
            s16x8 a;
            a[0] = (short)f2bf(lo.x); a[1] = (short)f2bf(lo.y);
            a[2] = (short)f2bf(lo.z); a[3] = (short)f2bf(lo.w);
            a[4] = (short)f2bf(hi.x); a[5] = (short)f2bf(hi.y);
            a[6] = (short)f2bf(hi.z); a[7] = (short)f2bf(hi.w);
            af[mi] = a;
        }
        if (kc < 11) {   // issue next chunk's A-loads; hidden under the MFMAs
#pragma unroll
            for (int mi = 0; mi < 2; mi++) {
                const float* ap = xb + (size_t)(jt[mi] * 16 + n16) * C_ + (ko + 32) + q4 * 8;
                a0[mi] = *reinterpret_cast<const float4*>(ap);
                a1[mi] = *reinterpret_cast<const float4*>(ap + 4);
            }
        }
#pragma unroll
        for (int ni = 0; ni < 12; ni++) {
            int row = ni * 16 + n16;
            s16x8 bf = *reinterpret_cast<const s16x8*>(&Wc[row * 32 + ((q4 ^ (row & 3)) * 8)]);
            if (ni < 8) {   // q,k: swapped -> lane = token
                acc[0][ni] = __builtin_amdgcn_mfma_f32_16x16x32_bf16(bf, af[0], acc[0][ni], 0, 0, 0);
                acc[1][ni] = __builtin_amdgcn_mfma_f32_16x16x32_bf16(bf, af[1], acc[1][ni], 0, 0, 0);
            } else {        // v: normal -> lane = d-col
                acc[0][ni] = __builtin_amdgcn_mfma_f32_16x16x32_bf16(af[0], bf, acc[0][ni], 0, 0, 0);
                acc[1][ni] = __builtin_amdgcn_mfma_f32_16x16x32_bf16(af[1], bf, acc[1][ni], 0, 0, 0);
            }
        }
    }

    // epilogue: k/vT scatter (verbatim proven), q kept in registers
    unsigned int qd[2][4][2];   // [tile][ni][dword]; all indices unroll-const
#pragma unroll
    for (int mi = 0; mi < 2; mi++) {
        int tile = jt[mi];
#pragma unroll
        for (int ni = 0; ni < 12; ni++) {
            ushort4 pk;
            pk.x = f2bf(acc[mi][ni][0]); pk.y = f2bf(acc[mi][ni][1]);
            pk.z = f2bf(acc[mi][ni][2]); pk.w = f2bf(acc[mi][ni][3]);
            if (ni < 4) {
                qd[mi][ni][0] = (unsigned int)pk.x | ((unsigned int)pk.y << 16);
                qd[mi][ni][1] = (unsigned int)pk.z | ((unsigned int)pk.w << 16);
            } else if (ni < 8) {
                int t = tile * 16 + n16;                       // lane = token
                int cp = (2 * (ni & 3) + (q4 >> 1)) ^ (n16 & 7);
                *reinterpret_cast<ushort4*>(&k_lds[t * 64 + cp * 8 + (q4 & 1) * 4]) = pk;
            } else {
                int d = (ni - 8) * 16 + n16;                   // lane = d
                int cp = (tile * 2 + (q4 >> 1)) ^ (d & 7);
                *reinterpret_cast<ushort4*>(&vT_lds[d * 256 + cp * 8 + (q4 & 1) * 4]) = pk;
            }
        }
    }

    // in-register q relayout: C/D frag (d = ni*16+q4*4+r) -> A-frag
    // (qa0: d = q4*8..+7, qa1: d = 32+q4*8..+7), same token row n16.
    s16x8 qa[2][2];
    {
        int addrA = (n16 + 32 * (q4 & 1)) * 4;
        int addrB = addrA + 64;
        bool hi = (q4 & 2) != 0;
#pragma unroll
        for (int mi = 0; mi < 2; mi++) {
#pragma unroll
            for (int half = 0; half < 2; half++) {
                unsigned int s0x = qd[mi][half * 2][0],     s0y = qd[mi][half * 2][1];
                unsigned int s1x = qd[mi][half * 2 + 1][0], s1y = qd[mi][half * 2 + 1][1];
                unsigned int A0x = (unsigned int)__builtin_amdgcn_ds_bpermute(addrA, (int)s0x);
                unsigned int A1x = (unsigned int)__builtin_amdgcn_ds_bpermute(addrA, (int)s1x);
                unsigned int A0y = (unsigned int)__builtin_amdgcn_ds_bpermute(addrA, (int)s0y);
                unsigned int A1y = (unsigned int)__builtin_amdgcn_ds_bpermute(addrA, (int)s1y);
                unsigned int B0x = (unsigned int)__builtin_amdgcn_ds_bpermute(addrB, (int)s0x);
                unsigned int B1x = (unsigned int)__builtin_amdgcn_ds_bpermute(addrB, (int)s1x);
                unsigned int B0y = (unsigned int)__builtin_amdgcn_ds_bpermute(addrB, (int)s0y);
                unsigned int B1y = (unsigned int)__builtin_amdgcn_ds_bpermute(addrB, (int)s1y);
                unsigned int t[4];
                t[0] = hi ? A1x : A0x;
                t[1] = hi ? A1y : A0y;
                t[2] = hi ? B1x : B0x;
                t[3] = hi ? B1y : B0y;
                s16x8 q;
                __builtin_memcpy(&q, t, 16);
                qa[mi][half] = q;
            }
        }
    }
    __syncthreads();

    // ---------------- Phase B: causal attention from LDS ----------------
    unsigned short* pw = smem + w * 640;   // aliases Wc region; safe post-barrier
    const f32x4 zero4 = (f32x4){0.f, 0.f, 0.f, 0.f};

#pragma unroll
    for (int tt = 0; tt < 2; tt++) {
        int j = jt[tt];
        int t0 = j * 16;
        s16x8 qa0 = qa[tt][0];
        s16x8 qa1 = qa[tt][1];

        f32x4 o[4];
        float l_lane[4];
#pragma unroll
        for (int i = 0; i < 4; i++) o[i] = zero4;
#pragma unroll
        for (int r = 0; r < 4; r++) l_lane[r] = 0.f;

        int nch = j / 2 + 1;
        for (int c = 0; c < nch; c++) {
            int s0 = c * 32;
            bool bAct = (s0 + 16) < (t0 + 16);
            int r0 = s0 + n16, r1 = s0 + 16 + n16;
            s16x8 k00 = *reinterpret_cast<const s16x8*>(&k_lds[r0 * 64 + ((q4 ^ (r0 & 7)) * 8)]);
            s16x8 k01 = *reinterpret_cast<const s16x8*>(&k_lds[r0 * 64 + (((q4 + 4) ^ (r0 & 7)) * 8)]);
            f32x4 sv0 = __builtin_amdgcn_mfma_f32_16x16x32_bf16(qa0, k00, zero4, 0, 0, 0);
            sv0 = __builtin_amdgcn_mfma_f32_16x16x32_bf16(qa1, k01, sv0, 0, 0, 0);
            f32x4 sv1 = zero4;
            if (bAct) {
                s16x8 k10 = *reinterpret_cast<const s16x8*>(&k_lds[r1 * 64 + ((q4 ^ (r1 & 7)) * 8)]);
                s16x8 k11 = *reinterpret_cast<const s16x8*>(&k_lds[r1 * 64 + (((q4 + 4) ^ (r1 & 7)) * 8)]);
                sv1 = __builtin_amdgcn_mfma_f32_16x16x32_bf16(qa0, k10, zero4, 0, 0, 0);
                sv1 = __builtin_amdgcn_mfma_f32_16x16x32_bf16(qa1, k11, sv1, 0, 0, 0);
            }
#pragma unroll
            for (int r = 0; r < 4; r++) {
                int t = t0 + q4 * 4 + r;
                float pA = (s0 + n16 <= t) ? __expf(sv0[r] * 0.125f) : 0.f;
                float pB = (bAct && (s0 + 16 + n16 <= t)) ? __expf(sv1[r] * 0.125f) : 0.f;
                l_lane[r] += pA + pB;
                pw[(q4 * 4 + r) * 40 + n16] = f2bf(pA);
                pw[(q4 * 4 + r) * 40 + 16 + n16] = f2bf(pB);
            }
            s16x8 pa = *reinterpret_cast<const s16x8*>(&pw[n16 * 40 + q4 * 8]);
#pragma unroll
            for (int dt = 0; dt < 4; dt++) {
                int d = dt * 16 + n16;
                int jp = (c * 4 + q4) ^ (d & 7);
                s16x8 vf = *reinterpret_cast<const s16x8*>(&vT_lds[d * 256 + jp * 8]);
                o[dt] = __builtin_amdgcn_mfma_f32_16x16x32_bf16(pa, vf, o[dt], 0, 0, 0);
            }
        }

        float linv[4];
#pragma unroll
        for (int r = 0; r < 4; r++) {
            float l = l_lane[r];
            l += __shfl_xor(l, 1);
            l += __shfl_xor(l, 2);
            l += __shfl_xor(l, 4);
            l += __shfl_xor(l, 8);
            linv[r] = 1.0f / l;
        }
#pragma unroll
        for (int dt = 0; dt < 4; dt++) {
            int col = h * 64 + dt * 16 + n16;
#pragma unroll
            for (int r = 0; r < 4; r++)
                Ows[(size_t)(b * T_ + t0 + q4 * 4 + r) * C_ + col] = f2bf(o[dt][r] * linv[r]);
        }
    }
}

// ---------------------------------------------------------------------------
// Kernel 2: output projection + bias -> f32.  (R5-exact: A-prefetch +
// DMA-staged B, grid (128, 3), wave = 32 rows x 128 cols, swapped MFMA.)
// ---------------------------------------------------------------------------
__global__ __launch_bounds__(256) void gemm_out(
    const unsigned short* __restrict__ A, const unsigned short* __restrict__ WTp,
    const float* __restrict__ bp, float* __restrict__ out) {
    __shared__ alignas(16) unsigned short Bt[6 * 128 * 32];   // 48 KB
    int m0 = blockIdx.x * 128;
    int n0 = blockIdx.y * 128;
    int tid = threadIdx.x;
    int w = tid >> 6, lane = tid & 63;
    int n16 = lane & 15, q4 = lane >> 4;

    f32x4 acc[2][8];
#pragma unroll
    for (int i = 0; i < 2; i++)
#pragma unroll
        for (int j = 0; j < 8; j++) acc[i][j] = (f32x4){0.f, 0.f, 0.f, 0.f};

    const unsigned short* a_base[2];
#pragma unroll
    for (int mi = 0; mi < 2; mi++)
        a_base[mi] = A + (size_t)(m0 + w * 32 + mi * 16 + n16) * C_ + q4 * 8;

    for (int half = 0; half < 2; half++) {
        int ko = half * 192;
        s16x8 af[2][6];
#pragma unroll
        for (int mi = 0; mi < 2; mi++)
#pragma unroll
            for (int ks = 0; ks < 6; ks++)
                af[mi][ks] = *reinterpret_cast<const s16x8*>(a_base[mi] + ko + ks * 32);
        if (half) __syncthreads();
#pragma unroll
        for (int i = 0; i < 12; i++) {
            int L = w * 768 + i * 64 + lane;
            int kstep = L >> 9;
            int rem = L & 511;
            int row = rem >> 2;
            int j = (rem & 3) ^ (row & 3);
            async_copy16(WTp + (size_t)(n0 + row) * C_ + ko + kstep * 32 + j * 8,
                         Bt + (size_t)(w * 768 + i * 64) * 8);
        }
        __syncthreads();
#pragma unroll
        for (int ks = 0; ks < 6; ks++) {
            s16x8 bf[8];
#pragma unroll
            for (int ni = 0; ni < 8; ni++) {
                int row = ni * 16 + n16;
                int jp = q4 ^ (row & 3);
                bf[ni] = *reinterpret_cast<const s16x8*>(&Bt[ks * 4096 + row * 32 + jp * 8]);
            }
#pragma unroll
            for (int mi = 0; mi < 2; mi++)
#pragma unroll
                for (int ni = 0; ni < 8; ni++)
                    acc[mi][ni] = __builtin_amdgcn_mfma_f32_16x16x32_bf16(
                        bf[ni], af[mi][ks], acc[mi][ni], 0, 0, 0);
        }
    }

#pragma unroll
    for (int mi = 0; mi < 2; mi++) {
        int tr = m0 + w * 32 + mi * 16 + n16;
#pragma unroll
        for (int ni = 0; ni < 8; ni++) {
            int c0 = n0 + ni * 16 + q4 * 4;
            float4 bias = *reinterpret_cast<const float4*>(&bp[c0]);
            float4 res;
            res.x = acc[mi][ni][0] + bias.x;
            res.y = acc[mi][ni][1] + bias.y;
            res.z = acc[mi][ni][2] + bias.z;
            res.w = acc[mi][ni][3] + bias.w;
            *reinterpret_cast<float4*>(&out[(size_t)tr * C_ + c0]) = res;
        }
    }
}

// ---------------------------------------------------------------------------
extern "C" void kernel_launch(void* const* d_in, const int* in_sizes, int n_in,
                              void* d_out, int out_size, void* d_ws, size_t ws_size,
                              hipStream_t stream) {
    const float* x  = (const float*)d_in[0];
    const float* Wq = (const float*)d_in[1];
    const float* Wk = (const float*)d_in[2];
    const float* Wv = (const float*)d_in[3];
    const float* Wp = (const float*)d_in[4];
    const float* bp = (const float*)d_in[5];
    float* out = (float*)d_out;

    char* ws = (char*)d_ws;
    size_t off = 0;
    auto alloc = [&](size_t bytes) -> unsigned short* {
        unsigned short* p = (unsigned short*)(ws + off);
        off += (bytes + 255) & ~(size_t)255;
        return p;
    };
    unsigned short* W3  = alloc((size_t)H_ * 192 * C_ * 2);  // 884 KB
    unsigned short* WTp = alloc((size_t)C_ * C_ * 2);        // 295 KB
    unsigned short* Ows = alloc((size_t)NTOK * C_ * 2);      // 12.6 MB

    transpose_weights<<<dim3(144, 19), dim3(256), 0, stream>>>(
        Wq, Wk, Wv, Wp, W3, WTp);
    fused_attn<<<dim3(B_ * H_), dim3(512), 0, stream>>>(x, W3, Ows);
    gemm_out<<<dim3(128, 3), dim3(256), 0, stream>>>(Ows, WTp, bp, out);
}

// Round 11
// 144.826 us; speedup vs baseline: 1.2099x; 1.0067x over previous
//
#include <hip/hip_runtime.h>
#include <stdint.h>

#define B_  64
#define T_  256
#define C_  384
#define H_  6
#define D_  64
#define NTOK (B_*T_)   // 16384

typedef float f32x4  __attribute__((ext_vector_type(4)));
typedef short s16x8  __attribute__((ext_vector_type(8)));

__device__ __forceinline__ unsigned short f2bf(float f) {
    unsigned int u;
    __builtin_memcpy(&u, &f, 4);
    u = u + 0x7FFFu + ((u >> 16) & 1u);   // RNE
    return (unsigned short)(u >> 16);
}

// async 16B global -> LDS (lane i lands at ldsbase + i*16)
__device__ __forceinline__ void async_copy16(const unsigned short* g, unsigned short* l) {
    __builtin_amdgcn_global_load_lds(
        (const __attribute__((address_space(1))) unsigned int*)g,
        (__attribute__((address_space(3))) unsigned int*)l, 16, 0, 0);
}

// ---------------------------------------------------------------------------
// Kernel 0: convert + transpose weights f32 [R][Cc] -> bf16 [Cc][R].
// z<18: per-(proj,head) 384x64 -> W3 [h][proj*64+d][k]; z==18: Wp -> WTp.
// (R5-exact)
// ---------------------------------------------------------------------------
__global__ __launch_bounds__(256) void transpose_weights(
    const float* __restrict__ Wq, const float* __restrict__ Wk,
    const float* __restrict__ Wv, const float* __restrict__ Wp,
    unsigned short* __restrict__ W3, unsigned short* __restrict__ WTp) {
    __shared__ float tile[32][33];
    int z = blockIdx.y;
    const float* in;
    unsigned short* out;
    int R, Cc;
    if (z < 18) {
        int proj = z / 6, h = z % 6;
        const float* Wsrc = proj == 0 ? Wq : (proj == 1 ? Wk : Wv);
        in = Wsrc + h * C_ * D_;
        out = W3 + (size_t)(h * 192 + proj * 64) * C_;
        R = C_; Cc = D_;
    } else {
        in = Wp; out = WTp; R = C_; Cc = C_;
    }
    int tilesC = Cc / 32;
    int tilesR = R / 32;
    int bx = blockIdx.x;
    if (bx >= tilesC * tilesR) return;
    int tr = bx / tilesC, tc = bx % tilesC;
    int tx = threadIdx.x & 31;
    int ty8 = threadIdx.x >> 5;
    int gx = tc * 32 + tx;
#pragma unroll
    for (int i = 0; i < 4; i++) {
        int gy = tr * 32 + ty8 + i * 8;
        tile[ty8 + i * 8][tx] = in[gy * Cc + gx];
    }
    __syncthreads();
#pragma unroll
    for (int i = 0; i < 4; i++) {
        int oy = tc * 32 + ty8 + i * 8;
        int ox = tr * 32 + tx;
        out[oy * R + ox] = f2bf(tile[tx][ty8 + i * 8]);
    }
}

// ---------------------------------------------------------------------------
// Kernel 1: FUSED per-(b,h) QKV projection + causal attention.  (R5-exact,
// the session's best verified state: fused 54us / total 145us — canary.)
// 76KB LDS -> 2 independent blocks/CU; 8-wave dual-tile; Wc [192][32] DMA
// staging; q in-register via ds_bpermute; pw aliases Wc post-barrier.
// Note: block h*64+b lands at dispatch position == b (mod 8) -> all 6 heads
// of batch-element b share one XCD; Ows[b] lines live in XCD (b%8)'s L2.
// ---------------------------------------------------------------------------
__global__ __launch_bounds__(512, 4) void fused_attn(
    const float* __restrict__ X, const unsigned short* __restrict__ W3,
    unsigned short* __restrict__ Ows) {
    __shared__ alignas(16) unsigned short smem[38912];   // 76 KB -> 2 blocks/CU
    unsigned short* Wc     = smem;            // [192][32] staging; pw aliases post-barrier
    unsigned short* k_lds  = smem + 6144;     // [256][64]
    unsigned short* vT_lds = k_lds + 16384;   // [64][256]

    int bh = blockIdx.x;
    int h = bh >> 6, b = bh & 63;
    int tid = threadIdx.x;
    int w = tid >> 6, lane = tid & 63;
    int n16 = lane & 15, q4 = lane >> 4;
    const int jt[2] = {w, 15 - w};            // this wave's token-tiles (both phases)

    const unsigned short* W3h = W3 + (size_t)h * 192 * C_;
    const float* xb = X + (size_t)b * T_ * C_;

    f32x4 acc[2][12];
#pragma unroll
    for (int i = 0; i < 2; i++)
#pragma unroll
        for (int jj = 0; jj < 12; jj++) acc[i][jj] = (f32x4){0.f, 0.f, 0.f, 0.f};

    // ---------------- Phase A: q/k/v projection, 12 chunks of K=32 --------
    float4 a0[2], a1[2];
#pragma unroll
    for (int mi = 0; mi < 2; mi++) {          // preload chunk 0 A-frags
        const float* ap = xb + (size_t)(jt[mi] * 16 + n16) * C_ + q4 * 8;
        a0[mi] = *reinterpret_cast<const float4*>(ap);
        a1[mi] = *reinterpret_cast<const float4*>(ap + 4);
    }

    for (int kc = 0; kc < 12; kc++) {
        int ko = kc * 32;
        if (kc) __syncthreads();   // prev chunk's readers done
        // stage W chunk [192 rows][4 units of 16B]; slot L: row=L>>2, phys
        // unit c=L&3 holds logical unit c^(row&3)
        {
            int L = w * 64 + lane;
            int row = L >> 2, c = L & 3;
            async_copy16(W3h + (size_t)row * C_ + ko + ((c ^ (row & 3)) * 8),
                         Wc + (size_t)L * 8);
            if (w < 4) {
                int L2 = 512 + w * 64 + lane;
                int row2 = L2 >> 2, c2 = L2 & 3;
                async_copy16(W3h + (size_t)row2 * C_ + ko + ((c2 ^ (row2 & 3)) * 8),
                             Wc + (size_t)L2 * 8);
            }
        }
        __syncthreads();   // drains DMA (+ A-loads issued one chunk ago)
        s16x8 af[2];
#pragma unroll
        for (int mi = 0; mi < 2; mi++) {
            float4 lo = a0[mi], hi = a1[mi];
            s16x8 a;
            a[0] = (short)f2bf(lo.x); a[1] = (short)f2bf(lo.y);
            a[2] = (short)f2bf(lo.z); a[3] = (short)f2bf(lo.w);
            a[4] = (short)f2bf(hi.x); a[5] = (short)f2bf(hi.y);
            a[6] = (short)f2bf(hi.z); a[7] = (short)f2bf(hi.w);
            af[mi] = a;
        }
        if (kc < 11) {   // issue next chunk's A-loads; hidden under the MFMAs
#pragma unroll
            for (int mi = 0; mi < 2; mi++) {
                const float* ap = xb + (size_t)(jt[mi] * 16 + n16) * C_ + (ko + 32) + q4 * 8;
                a0[mi] = *reinterpret_cast<const float4*>(ap);
                a1[mi] = *reinterpret_cast<const float4*>(ap + 4);
            }
        }
#pragma unroll
        for (int ni = 0; ni < 12; ni++) {
            int row = ni * 16 + n16;
            s16x8 bf = *reinterpret_cast<const s16x8*>(&Wc[row * 32 + ((q4 ^ (row & 3)) * 8)]);
            if (ni < 8) {   // q,k: swapped -> lane = token
                acc[0][ni] = __builtin_amdgcn_mfma_f32_16x16x32_bf16(bf, af[0], acc[0][ni], 0, 0, 0);
                acc[1][ni] = __builtin_amdgcn_mfma_f32_16x16x32_bf16(bf, af[1], acc[1][ni], 0, 0, 0);
            } else {        // v: normal -> lane = d-col
                acc[0][ni] = __builtin_amdgcn_mfma_f32_16x16x32_bf16(af[0], bf, acc[0][ni], 0, 0, 0);
                acc[1][ni] = __builtin_amdgcn_mfma_f32_16x16x32_bf16(af[1], bf, acc[1][ni], 0, 0, 0);
            }
        }
    }

    // epilogue: k/vT scatter (verbatim proven), q kept in registers
    unsigned int qd[2][4][2];   // [tile][ni][dword]; all indices unroll-const
#pragma unroll
    for (int mi = 0; mi < 2; mi++) {
        int tile = jt[mi];
#pragma unroll
        for (int ni = 0; ni < 12; ni++) {
            ushort4 pk;
            pk.x = f2bf(acc[mi][ni][0]); pk.y = f2bf(acc[mi][ni][1]);
            pk.z = f2bf(acc[mi][ni][2]); pk.w = f2bf(acc[mi][ni][3]);
            if (ni < 4) {
                qd[mi][ni][0] = (unsigned int)pk.x | ((unsigned int)pk.y << 16);
                qd[mi][ni][1] = (unsigned int)pk.z | ((unsigned int)pk.w << 16);
            } else if (ni < 8) {
                int t = tile * 16 + n16;                       // lane = token
                int cp = (2 * (ni & 3) + (q4 >> 1)) ^ (n16 & 7);
                *reinterpret_cast<ushort4*>(&k_lds[t * 64 + cp * 8 + (q4 & 1) * 4]) = pk;
            } else {
                int d = (ni - 8) * 16 + n16;                   // lane = d
                int cp = (tile * 2 + (q4 >> 1)) ^ (d & 7);
                *reinterpret_cast<ushort4*>(&vT_lds[d * 256 + cp * 8 + (q4 & 1) * 4]) = pk;
            }
        }
    }

    // in-register q relayout: C/D frag (d = ni*16+q4*4+r) -> A-frag
    // (qa0: d = q4*8..+7, qa1: d = 32+q4*8..+7), same token row n16.
    s16x8 qa[2][2];
    {
        int addrA = (n16 + 32 * (q4 & 1)) * 4;
        int addrB = addrA + 64;
        bool hi = (q4 & 2) != 0;
#pragma unroll
        for (int mi = 0; mi < 2; mi++) {
#pragma unroll
            for (int half = 0; half < 2; half++) {
                unsigned int s0x = qd[mi][half * 2][0],     s0y = qd[mi][half * 2][1];
                unsigned int s1x = qd[mi][half * 2 + 1][0], s1y = qd[mi][half * 2 + 1][1];
                unsigned int A0x = (unsigned int)__builtin_amdgcn_ds_bpermute(addrA, (int)s0x);
                unsigned int A1x = (unsigned int)__builtin_amdgcn_ds_bpermute(addrA, (int)s1x);
                unsigned int A0y = (unsigned int)__builtin_amdgcn_ds_bpermute(addrA, (int)s0y);
                unsigned int A1y = (unsigned int)__builtin_amdgcn_ds_bpermute(addrA, (int)s1y);
                unsigned int B0x = (unsigned int)__builtin_amdgcn_ds_bpermute(addrB, (int)s0x);
                unsigned int B1x = (unsigned int)__builtin_amdgcn_ds_bpermute(addrB, (int)s1x);
                unsigned int B0y = (unsigned int)__builtin_amdgcn_ds_bpermute(addrB, (int)s0y);
                unsigned int B1y = (unsigned int)__builtin_amdgcn_ds_bpermute(addrB, (int)s1y);
                unsigned int t[4];
                t[0] = hi ? A1x : A0x;
                t[1] = hi ? A1y : A0y;
                t[2] = hi ? B1x : B0x;
                t[3] = hi ? B1y : B0y;
                s16x8 q;
                __builtin_memcpy(&q, t, 16);
                qa[mi][half] = q;
            }
        }
    }
    __syncthreads();

    // ---------------- Phase B: causal attention from LDS ----------------
    unsigned short* pw = smem + w * 640;   // aliases Wc region; safe post-barrier
    const f32x4 zero4 = (f32x4){0.f, 0.f, 0.f, 0.f};

#pragma unroll
    for (int tt = 0; tt < 2; tt++) {
        int j = jt[tt];
        int t0 = j * 16;
        s16x8 qa0 = qa[tt][0];
        s16x8 qa1 = qa[tt][1];

        f32x4 o[4];
        float l_lane[4];
#pragma unroll
        for (int i = 0; i < 4; i++) o[i] = zero4;
#pragma unroll
        for (int r = 0; r < 4; r++) l_lane[r] = 0.f;

        int nch = j / 2 + 1;
        for (int c = 0; c < nch; c++) {
            int s0 = c * 32;
            bool bAct = (s0 + 16) < (t0 + 16);
            int r0 = s0 + n16, r1 = s0 + 16 + n16;
            s16x8 k00 = *reinterpret_cast<const s16x8*>(&k_lds[r0 * 64 + ((q4 ^ (r0 & 7)) * 8)]);
            s16x8 k01 = *reinterpret_cast<const s16x8*>(&k_lds[r0 * 64 + (((q4 + 4) ^ (r0 & 7)) * 8)]);
            f32x4 sv0 = __builtin_amdgcn_mfma_f32_16x16x32_bf16(qa0, k00, zero4, 0, 0, 0);
            sv0 = __builtin_amdgcn_mfma_f32_16x16x32_bf16(qa1, k01, sv0, 0, 0, 0);
            f32x4 sv1 = zero4;
            if (bAct) {
                s16x8 k10 = *reinterpret_cast<const s16x8*>(&k_lds[r1 * 64 + ((q4 ^ (r1 & 7)) * 8)]);
                s16x8 k11 = *reinterpret_cast<const s16x8*>(&k_lds[r1 * 64 + (((q4 + 4) ^ (r1 & 7)) * 8)]);
                sv1 = __builtin_amdgcn_mfma_f32_16x16x32_bf16(qa0, k10, zero4, 0, 0, 0);
                sv1 = __builtin_amdgcn_mfma_f32_16x16x32_bf16(qa1, k11, sv1, 0, 0, 0);
            }
#pragma unroll
            for (int r = 0; r < 4; r++) {
                int t = t0 + q4 * 4 + r;
                float pA = (s0 + n16 <= t) ? __expf(sv0[r] * 0.125f) : 0.f;
                float pB = (bAct && (s0 + 16 + n16 <= t)) ? __expf(sv1[r] * 0.125f) : 0.f;
                l_lane[r] += pA + pB;
                pw[(q4 * 4 + r) * 40 + n16] = f2bf(pA);
                pw[(q4 * 4 + r) * 40 + 16 + n16] = f2bf(pB);
            }
            s16x8 pa = *reinterpret_cast<const s16x8*>(&pw[n16 * 40 + q4 * 8]);
#pragma unroll
            for (int dt = 0; dt < 4; dt++) {
                int d = dt * 16 + n16;
                int jp = (c * 4 + q4) ^ (d & 7);
                s16x8 vf = *reinterpret_cast<const s16x8*>(&vT_lds[d * 256 + jp * 8]);
                o[dt] = __builtin_amdgcn_mfma_f32_16x16x32_bf16(pa, vf, o[dt], 0, 0, 0);
            }
        }

        float linv[4];
#pragma unroll
        for (int r = 0; r < 4; r++) {
            float l = l_lane[r];
            l += __shfl_xor(l, 1);
            l += __shfl_xor(l, 2);
            l += __shfl_xor(l, 4);
            l += __shfl_xor(l, 8);
            linv[r] = 1.0f / l;
        }
#pragma unroll
        for (int dt = 0; dt < 4; dt++) {
            int col = h * 64 + dt * 16 + n16;
#pragma unroll
            for (int r = 0; r < 4; r++)
                Ows[(size_t)(b * T_ + t0 + q4 * 4 + r) * C_ + col] = f2bf(o[dt][r] * linv[r]);
        }
    }
}

// ---------------------------------------------------------------------------
// Kernel 2: output projection + bias -> f32.  R11: XCD-aware m-block remap.
// fused_attn writes Ows[b] into XCD (b%8)'s L2 (its blocks h*64+b sit at
// dispatch position == b mod 8).  Natural gemm mapping puts the block for
// rows of b at position bx=2b(+1) -> XCD (2b)%8 != b%8 -> cross-XCD L2 miss
// -> ~12.6MB HBM re-fetch + unhidden latency on the unstaged A-loads.
// Remap: position p handles mb = 16*(q>>1) + 2r + (q&1) (r=p&7, q=p>>3) --
// bijective on 0..127 with mb/2 == p (mod 8), so the reader of b sits on
// XCD b%8 where the producer's lines live.  by-slices keep position == p
// (mod 8) since 128 == 0 mod 8 -> all 3 n-slices of the same rows still
// share one XCD.  Pure index permutation: no arithmetic/sync change.
// ---------------------------------------------------------------------------
__global__ __launch_bounds__(256) void gemm_out(
    const unsigned short* __restrict__ A, const unsigned short* __restrict__ WTp,
    const float* __restrict__ bp, float* __restrict__ out) {
    __shared__ alignas(16) unsigned short Bt[6 * 128 * 32];   // 48 KB
    int p = blockIdx.x;
    int rr = p & 7, qq = p >> 3;
    int mb = ((qq >> 1) << 4) + (rr << 1) + (qq & 1);   // bijective remap
    int m0 = mb * 128;
    int n0 = blockIdx.y * 128;
    int tid = threadIdx.x;
    int w = tid >> 6, lane = tid & 63;
    int n16 = lane & 15, q4 = lane >> 4;

    f32x4 acc[2][8];
#pragma unroll
    for (int i = 0; i < 2; i++)
#pragma unroll
        for (int j = 0; j < 8; j++) acc[i][j] = (f32x4){0.f, 0.f, 0.f, 0.f};

    const unsigned short* a_base[2];
#pragma unroll
    for (int mi = 0; mi < 2; mi++)
        a_base[mi] = A + (size_t)(m0 + w * 32 + mi * 16 + n16) * C_ + q4 * 8;

    for (int half = 0; half < 2; half++) {
        int ko = half * 192;
        s16x8 af[2][6];
#pragma unroll
        for (int mi = 0; mi < 2; mi++)
#pragma unroll
            for (int ks = 0; ks < 6; ks++)
                af[mi][ks] = *reinterpret_cast<const s16x8*>(a_base[mi] + ko + ks * 32);
        if (half) __syncthreads();
#pragma unroll
        for (int i = 0; i < 12; i++) {
            int L = w * 768 + i * 64 + lane;
            int kstep = L >> 9;
            int rem = L & 511;
            int row = rem >> 2;
            int j = (rem & 3) ^ (row & 3);
            async_copy16(WTp + (size_t)(n0 + row) * C_ + ko + kstep * 32 + j * 8,
                         Bt + (size_t)(w * 768 + i * 64) * 8);
        }
        __syncthreads();
#pragma unroll
        for (int ks = 0; ks < 6; ks++) {
            s16x8 bf[8];
#pragma unroll
            for (int ni = 0; ni < 8; ni++) {
                int row = ni * 16 + n16;
                int jp = q4 ^ (row & 3);
                bf[ni] = *reinterpret_cast<const s16x8*>(&Bt[ks * 4096 + row * 32 + jp * 8]);
            }
#pragma unroll
            for (int mi = 0; mi < 2; mi++)
#pragma unroll
                for (int ni = 0; ni < 8; ni++)
                    acc[mi][ni] = __builtin_amdgcn_mfma_f32_16x16x32_bf16(
                        bf[ni], af[mi][ks], acc[mi][ni], 0, 0, 0);
        }
    }

#pragma unroll
    for (int mi = 0; mi < 2; mi++) {
        int tr = m0 + w * 32 + mi * 16 + n16;
#pragma unroll
        for (int ni = 0; ni < 8; ni++) {
            int c0 = n0 + ni * 16 + q4 * 4;
            float4 bias = *reinterpret_cast<const float4*>(&bp[c0]);
            float4 res;
            res.x = acc[mi][ni][0] + bias.x;
            res.y = acc[mi][ni][1] + bias.y;
            res.z = acc[mi][ni][2] + bias.z;
            res.w = acc[mi][ni][3] + bias.w;
            *reinterpret_cast<float4*>(&out[(size_t)tr * C_ + c0]) = res;
        }
    }
}

// ---------------------------------------------------------------------------
extern "C" void kernel_launch(void* const* d_in, const int* in_sizes, int n_in,
                              void* d_out, int out_size, void* d_ws, size_t ws_size,
                              hipStream_t stream) {
    const float* x  = (const float*)d_in[0];
    const float* Wq = (const float*)d_in[1];
    const float* Wk = (const float*)d_in[2];
    const float* Wv = (const float*)d_in[3];
    const float* Wp = (const float*)d_in[4];
    const float* bp = (const float*)d_in[5];
    float* out = (float*)d_out;

    char* ws = (char*)d_ws;
    size_t off = 0;
    auto alloc = [&](size_t bytes) -> unsigned short* {
        unsigned short* p = (unsigned short*)(ws + off);
        off += (bytes + 255) & ~(size_t)255;
        return p;
    };
    unsigned short* W3  = alloc((size_t)H_ * 192 * C_ * 2);  // 884 KB
    unsigned short* WTp = alloc((size_t)C_ * C_ * 2);        // 295 KB
    unsigned short* Ows = alloc((size_t)NTOK * C_ * 2);      // 12.6 MB

    transpose_weights<<<dim3(144, 19), dim3(256), 0, stream>>>(
        Wq, Wk, Wv, Wp, W3, WTp);
    fused_attn<<<dim3(B_ * H_), dim3(512), 0, stream>>>(x, W3, Ows);
    gemm_out<<<dim3(128, 3), dim3(256), 0, stream>>>(Ows, WTp, bp, out);
}